// Round 2
// baseline (1709.345 us; speedup 1.0000x reference)
//
#include <hip/hip_runtime.h>
#include <hip/hip_bf16.h>

typedef unsigned short ushort_t;
typedef __attribute__((ext_vector_type(8))) short short8;
typedef __attribute__((ext_vector_type(4))) float f32x4;

#define SEQ 4096
#define EMB 1024
#define HEADS 16
#define DH 128
#define SCALE 0.088388347648318447f  /* 1/sqrt(128) */

__device__ __forceinline__ ushort_t f2bf(float f) {
    union { float f; unsigned u; } v; v.f = f;
    unsigned r = v.u + 0x7fffu + ((v.u >> 16) & 1u);
    return (ushort_t)(r >> 16);
}

// xp = x + positional_encoding, cast to bf16
__global__ __launch_bounds__(256) void prep_x_kernel(
    const float* __restrict__ x, ushort_t* __restrict__ xp)
{
    const int s = blockIdx.x;
    const int c = blockIdx.y * 256 + threadIdx.x;
    const int expo = c & ~1;                 // 2*floor(c/2)
    // denominator = EMB / 10000^expo ; overflows to inf -> denom 0 (matches jax fp32)
    float p = powf(10000.0f, (float)expo);
    float denom = (float)EMB / p;            // inf -> 0
    float ang = (float)s * denom;
    float pe = (c & 1) ? cosf(ang) : sinf(ang);
    xp[(size_t)s * EMB + c] = f2bf(x[(size_t)s * EMB + c] + pe);
}

// W[b][k][n] f32 -> Wt[b][n][k] bf16
__global__ __launch_bounds__(256) void transpose_w_kernel(
    const float* __restrict__ W, ushort_t* __restrict__ Wt, int Kd, int Nd)
{
    const int b = blockIdx.z;
    const int idx = blockIdx.x * 256 + threadIdx.x;
    if (idx >= Kd * Nd) return;
    const int n = idx / Kd, k = idx % Kd;
    Wt[(size_t)b * Nd * Kd + idx] = f2bf(W[(size_t)b * Kd * Nd + (size_t)k * Nd + n]);
}

// C = A(bf16, MxK) @ Bt(bf16, batch x N x K)^T + bias(batch x N)
// MODE 0: bf16 out [batch][M][N]; MODE 1: bf16 out [batch][N][M]; MODE 2: f32 out [M][N] (batch==1)
template <int MODE>
__global__ __launch_bounds__(256) void gemm_bias_kernel(
    const ushort_t* __restrict__ A, const ushort_t* __restrict__ Bt,
    const float* __restrict__ bias, void* __restrict__ Cout,
    int M, int N, int K)
{
    const int mb = blockIdx.x, nb = blockIdx.y, h = blockIdx.z;
    const int tid = threadIdx.x;
    const int w = tid >> 6;
    const int l = tid & 63;
    const int l15 = l & 15, lhi = l >> 4;

    const ushort_t* Bh = Bt + (size_t)h * N * K;

    f32x4 acc[4];
#pragma unroll
    for (int g = 0; g < 4; ++g) acc[g] = f32x4{0.f, 0.f, 0.f, 0.f};

    const int arow = mb * 64 + w * 16 + l15;
    const ushort_t* Aptr = A + (size_t)arow * K + lhi * 8;

    for (int kc = 0; kc < K; kc += 32) {
        short8 a = *(const short8*)(Aptr + kc);
#pragma unroll
        for (int g = 0; g < 4; ++g) {
            const int col = nb * 64 + g * 16 + l15;
            short8 b = *(const short8*)(Bh + (size_t)col * K + kc + lhi * 8);
            acc[g] = __builtin_amdgcn_mfma_f32_16x16x32_bf16(a, b, acc[g], 0, 0, 0);
        }
    }

#pragma unroll
    for (int g = 0; g < 4; ++g) {
        const int col = nb * 64 + g * 16 + l15;
        const float bv = bias[(size_t)h * N + col];
#pragma unroll
        for (int r = 0; r < 4; ++r) {
            const int row = mb * 64 + w * 16 + 4 * lhi + r;
            const float val = acc[g][r] + bv;
            if (MODE == 0)
                ((ushort_t*)Cout)[((size_t)h * M + row) * N + col] = f2bf(val);
            else if (MODE == 1)
                ((ushort_t*)Cout)[((size_t)h * N + col) * M + row] = f2bf(val);
            else
                ((float*)Cout)[(size_t)row * N + col] = val;
        }
    }
}

// Flash attention: Q[h][s][d], K[h][t][d], Vt[h][d][t] (bf16) -> att[s][h*128+d] (bf16)
__global__ __launch_bounds__(256) void attn_kernel(
    const ushort_t* __restrict__ Q, const ushort_t* __restrict__ K,
    const ushort_t* __restrict__ Vt, ushort_t* __restrict__ att)
{
    const int qb = blockIdx.x;       // 64-row q block
    const int h = blockIdx.y;
    const int tid = threadIdx.x;
    const int w = tid >> 6;
    const int l = tid & 63;
    const int l15 = l & 15, lhi = l >> 4;

    __shared__ ushort_t P[4][16][64];   // per-wave P tile

    const ushort_t* Qh = Q + (size_t)h * SEQ * DH;
    const ushort_t* Kh = K + (size_t)h * SEQ * DH;
    const ushort_t* Vh = Vt + (size_t)h * DH * SEQ;

    // Q fragments: rows qb*64 + w*16 + (0..15), all 128 d
    short8 qf[4];
    const int qrow = qb * 64 + w * 16 + l15;
#pragma unroll
    for (int c = 0; c < 4; ++c)
        qf[c] = *(const short8*)(Qh + (size_t)qrow * DH + c * 32 + lhi * 8);

    f32x4 o[8];
#pragma unroll
    for (int g = 0; g < 8; ++g) o[g] = f32x4{0.f, 0.f, 0.f, 0.f};
    float mrun[4], lrun[4];
#pragma unroll
    for (int r = 0; r < 4; ++r) { mrun[r] = -1e30f; lrun[r] = 0.f; }

    for (int t0 = 0; t0 < SEQ; t0 += 64) {
        // QK^T for 64 keys
        f32x4 sc[4];
#pragma unroll
        for (int kg = 0; kg < 4; ++kg) sc[kg] = f32x4{0.f, 0.f, 0.f, 0.f};
#pragma unroll
        for (int kg = 0; kg < 4; ++kg) {
            const int trow = t0 + kg * 16 + l15;
#pragma unroll
            for (int c = 0; c < 4; ++c) {
                short8 kf = *(const short8*)(Kh + (size_t)trow * DH + c * 32 + lhi * 8);
                sc[kg] = __builtin_amdgcn_mfma_f32_16x16x32_bf16(qf[c], kf, sc[kg], 0, 0, 0);
            }
        }
        // online softmax; score rows r live at row 4*lhi+r, cols kg*16+l15
        float corr[4];
#pragma unroll
        for (int r = 0; r < 4; ++r) {
            float s0 = sc[0][r] * SCALE, s1 = sc[1][r] * SCALE,
                  s2 = sc[2][r] * SCALE, s3 = sc[3][r] * SCALE;
            float mx = fmaxf(fmaxf(s0, s1), fmaxf(s2, s3));
#pragma unroll
            for (int off = 1; off < 16; off <<= 1)
                mx = fmaxf(mx, __shfl_xor(mx, off, 64));
            const float mnew = fmaxf(mrun[r], mx);
            corr[r] = __expf(mrun[r] - mnew);
            const float p0 = __expf(s0 - mnew);
            const float p1 = __expf(s1 - mnew);
            const float p2 = __expf(s2 - mnew);
            const float p3 = __expf(s3 - mnew);
            const int ri = 4 * lhi + r;
            P[w][ri][0 * 16 + l15] = f2bf(p0);
            P[w][ri][1 * 16 + l15] = f2bf(p1);
            P[w][ri][2 * 16 + l15] = f2bf(p2);
            P[w][ri][3 * 16 + l15] = f2bf(p3);
            float ps = p0 + p1 + p2 + p3;
#pragma unroll
            for (int off = 1; off < 16; off <<= 1)
                ps += __shfl_xor(ps, off, 64);
            lrun[r] = lrun[r] * corr[r] + ps;
            mrun[r] = mnew;
        }
        // rescale O
#pragma unroll
        for (int g = 0; g < 8; ++g)
#pragma unroll
            for (int r = 0; r < 4; ++r) o[g][r] *= corr[r];

        __syncthreads();   // (P is wave-private; barrier is belt-and-suspenders)

        // PV: A = P (rows=q, k=t), B = Vt
#pragma unroll
        for (int c2 = 0; c2 < 2; ++c2) {
            short8 pa = *(const short8*)(&P[w][l15][c2 * 32 + lhi * 8]);
#pragma unroll
            for (int g = 0; g < 8; ++g) {
                const int dcol = g * 16 + l15;
                short8 vf = *(const short8*)(Vh + (size_t)dcol * SEQ + t0 + c2 * 32 + lhi * 8);
                o[g] = __builtin_amdgcn_mfma_f32_16x16x32_bf16(pa, vf, o[g], 0, 0, 0);
            }
        }
        __syncthreads();
    }

    // epilogue: divide by l, write att[s][h*128+d]
#pragma unroll
    for (int r = 0; r < 4; ++r) {
        const float inv = 1.0f / lrun[r];
        const int row = qb * 64 + w * 16 + 4 * lhi + r;
#pragma unroll
        for (int g = 0; g < 8; ++g) {
            const int col = h * DH + g * 16 + l15;
            att[(size_t)row * (HEADS * DH) + col] = f2bf(o[g][r] * inv);
        }
    }
}

extern "C" void kernel_launch(void* const* d_in, const int* in_sizes, int n_in,
                              void* d_out, int out_size, void* d_ws, size_t ws_size,
                              hipStream_t stream) {
    const float* x  = (const float*)d_in[0];
    const float* Wq = (const float*)d_in[1];
    const float* bq = (const float*)d_in[2];
    const float* Wk = (const float*)d_in[3];
    const float* bk = (const float*)d_in[4];
    const float* Wv = (const float*)d_in[5];
    const float* bv = (const float*)d_in[6];
    const float* Wo = (const float*)d_in[7];
    const float* bo = (const float*)d_in[8];
    float* out = (float*)d_out;

    ushort_t* ws = (ushort_t*)d_ws;
    ushort_t* xp   = ws;                                   // 4096*1024
    ushort_t* Wqt  = xp  + (size_t)SEQ * EMB;              // 16*128*1024
    ushort_t* Wkt  = Wqt + (size_t)HEADS * DH * EMB;
    ushort_t* Wvt  = Wkt + (size_t)HEADS * DH * EMB;
    ushort_t* Wot  = Wvt + (size_t)HEADS * DH * EMB;       // 1024*2048
    ushort_t* Qb   = Wot + (size_t)EMB * (HEADS * DH);     // 16*4096*128
    ushort_t* Kb   = Qb  + (size_t)HEADS * SEQ * DH;
    ushort_t* Vtb  = Kb  + (size_t)HEADS * SEQ * DH;
    ushort_t* attb = Vtb + (size_t)HEADS * SEQ * DH;       // 4096*2048

    prep_x_kernel<<<dim3(SEQ, EMB / 256), 256, 0, stream>>>(x, xp);

    transpose_w_kernel<<<dim3((EMB * DH + 255) / 256, 1, HEADS), 256, 0, stream>>>(Wq, Wqt, EMB, DH);
    transpose_w_kernel<<<dim3((EMB * DH + 255) / 256, 1, HEADS), 256, 0, stream>>>(Wk, Wkt, EMB, DH);
    transpose_w_kernel<<<dim3((EMB * DH + 255) / 256, 1, HEADS), 256, 0, stream>>>(Wv, Wvt, EMB, DH);
    transpose_w_kernel<<<dim3((2048 * 1024 + 255) / 256, 1, 1), 256, 0, stream>>>(Wo, Wot, HEADS * DH, EMB);

    // Q, K: [h][s][d] bf16; V: [h][d][s] bf16
    gemm_bias_kernel<0><<<dim3(SEQ / 64, DH / 64, HEADS), 256, 0, stream>>>(xp, Wqt, bq, Qb, SEQ, DH, EMB);
    gemm_bias_kernel<0><<<dim3(SEQ / 64, DH / 64, HEADS), 256, 0, stream>>>(xp, Wkt, bk, Kb, SEQ, DH, EMB);
    gemm_bias_kernel<1><<<dim3(SEQ / 64, DH / 64, HEADS), 256, 0, stream>>>(xp, Wvt, bv, Vtb, SEQ, DH, EMB);

    attn_kernel<<<dim3(SEQ / 64, HEADS), 256, 0, stream>>>(Qb, Kb, Vtb, attb);

    // out = att @ Wo + bo (fp32 out)
    gemm_bias_kernel<2><<<dim3(SEQ / 64, EMB / 64, 1), 256, 0, stream>>>(attb, Wot, bo, out, SEQ, EMB, HEADS * DH);
}

// Round 5
// 1023.241 us; speedup vs baseline: 1.6705x; 1.6705x over previous
//
#include <hip/hip_runtime.h>
#include <hip/hip_bf16.h>

typedef unsigned short ushort_t;
typedef __attribute__((ext_vector_type(8))) short short8;
typedef __attribute__((ext_vector_type(4))) float f32x4;

#define SEQ 4096
#define EMB 1024
#define HEADS 16
#define DH 128
#define SCALE 0.088388347648318447f  /* 1/sqrt(128) */

__device__ __forceinline__ ushort_t f2bf(float f) {
    union { float f; unsigned u; } v; v.f = f;
    unsigned r = v.u + 0x7fffu + ((v.u >> 16) & 1u);
    return (ushort_t)(r >> 16);
}

// async global->LDS, 16B per lane; lds base must be wave-uniform (dest = base + lane*16)
__device__ __forceinline__ void gload_lds16(const ushort_t* g, ushort_t* l) {
    __builtin_amdgcn_global_load_lds(
        (const __attribute__((address_space(1))) void*)g,
        (__attribute__((address_space(3))) void*)l, 16, 0, 0);
}

// xp = x + positional_encoding, cast to bf16
__global__ __launch_bounds__(256) void prep_x_kernel(
    const float* __restrict__ x, ushort_t* __restrict__ xp)
{
    const int s = blockIdx.x;
    const int c = blockIdx.y * 256 + threadIdx.x;
    const int expo = c & ~1;                 // 2*floor(c/2)
    // denominator = EMB / 10000^expo ; overflows to inf -> denom 0 (matches jax fp32)
    float p = powf(10000.0f, (float)expo);
    float denom = (float)EMB / p;            // inf -> 0
    float ang = (float)s * denom;
    float pe = (c & 1) ? cosf(ang) : sinf(ang);
    xp[(size_t)s * EMB + c] = f2bf(x[(size_t)s * EMB + c] + pe);
}

// W[b][k][n] f32 -> Wt[b][n][k] bf16
__global__ __launch_bounds__(256) void transpose_w_kernel(
    const float* __restrict__ W, ushort_t* __restrict__ Wt, int Kd, int Nd)
{
    const int b = blockIdx.z;
    const int idx = blockIdx.x * 256 + threadIdx.x;
    if (idx >= Kd * Nd) return;
    const int n = idx / Kd, k = idx % Kd;
    Wt[(size_t)b * Nd * Kd + idx] = f2bf(W[(size_t)b * Kd * Nd + (size_t)k * Nd + n]);
}

// C = A(bf16, MxK) @ Bt(bf16, batch x N x K)^T + bias(batch x N)
// MODE 0: bf16 out [batch][M][N]; MODE 1: bf16 out [batch][N][M]; MODE 2: f32 out [M][N] (batch==1)
template <int MODE>
__global__ __launch_bounds__(256) void gemm_bias_kernel(
    const ushort_t* __restrict__ A, const ushort_t* __restrict__ Bt,
    const float* __restrict__ bias, void* __restrict__ Cout,
    int M, int N, int K)
{
    const int mb = blockIdx.x, nb = blockIdx.y, h = blockIdx.z;
    const int tid = threadIdx.x;
    const int w = tid >> 6;
    const int l = tid & 63;
    const int l15 = l & 15, lhi = l >> 4;

    const ushort_t* Bh = Bt + (size_t)h * N * K;

    f32x4 acc[4];
#pragma unroll
    for (int g = 0; g < 4; ++g) acc[g] = f32x4{0.f, 0.f, 0.f, 0.f};

    const int arow = mb * 64 + w * 16 + l15;
    const ushort_t* Aptr = A + (size_t)arow * K + lhi * 8;

    for (int kc = 0; kc < K; kc += 32) {
        short8 a = *(const short8*)(Aptr + kc);
#pragma unroll
        for (int g = 0; g < 4; ++g) {
            const int col = nb * 64 + g * 16 + l15;
            short8 b = *(const short8*)(Bh + (size_t)col * K + kc + lhi * 8);
            acc[g] = __builtin_amdgcn_mfma_f32_16x16x32_bf16(a, b, acc[g], 0, 0, 0);
        }
    }

#pragma unroll
    for (int g = 0; g < 4; ++g) {
        const int col = nb * 64 + g * 16 + l15;
        const float bv = bias[(size_t)h * N + col];
#pragma unroll
        for (int r = 0; r < 4; ++r) {
            const int row = mb * 64 + w * 16 + 4 * lhi + r;
            const float val = acc[g][r] + bv;
            if (MODE == 0)
                ((ushort_t*)Cout)[((size_t)h * M + row) * N + col] = f2bf(val);
            else if (MODE == 1)
                ((ushort_t*)Cout)[((size_t)h * N + col) * M + row] = f2bf(val);
            else
                ((float*)Cout)[(size_t)row * N + col] = val;
        }
    }
}

// Flash attention: Q[h][s][d], K[h][t][d], Vt[h][d][t] (bf16) -> att[s][h*128+d] (bf16)
// K/V tiles double-buffered in LDS (global_load_lds w16, XOR-swizzled via pre-swizzled
// global source: LDS[row][c'] = global[row][c' ^ (row&7)], 16B chunks).
__global__ __launch_bounds__(256) void attn_kernel(
    const ushort_t* __restrict__ Q, const ushort_t* __restrict__ K,
    const ushort_t* __restrict__ Vt, ushort_t* __restrict__ att)
{
    const int qb = blockIdx.x;       // 64-row q block
    const int h = blockIdx.y;
    const int tid = threadIdx.x;
    const int w = tid >> 6;
    const int l = tid & 63;
    const int l15 = l & 15, lhi = l >> 4;

    __shared__ ushort_t Kbuf[2][64 * 128];   // [t][d], row stride 128 elem (256B), swizzled
    __shared__ ushort_t Vbuf[2][128 * 64];   // [d][t], row stride  64 elem (128B), swizzled
    __shared__ ushort_t P[4][16][64];        // per-wave P tile

    const ushort_t* Qh = Q + (size_t)h * SEQ * DH;
    const ushort_t* Kh = K + (size_t)h * SEQ * DH;
    const ushort_t* Vh = Vt + (size_t)h * DH * SEQ;

    // Q fragments: rows qb*64 + w*16 + (0..15), all 128 d
    short8 qf[4];
    const int qrow = qb * 64 + w * 16 + l15;
#pragma unroll
    for (int c = 0; c < 4; ++c)
        qf[c] = *(const short8*)(Qh + (size_t)qrow * DH + c * 32 + lhi * 8);

    f32x4 o[8];
#pragma unroll
    for (int g = 0; g < 8; ++g) o[g] = f32x4{0.f, 0.f, 0.f, 0.f};
    float mrun[4], lrun[4];
#pragma unroll
    for (int r = 0; r < 4; ++r) { mrun[r] = -1e30f; lrun[r] = 0.f; }

    // stage one 64-key tile (K: 16KB, V: 16KB) into buf; all 256 threads, 8x 16B each
    auto stage = [&](int buf, int t0) {
#pragma unroll
        for (int r = 0; r < 4; ++r) {
            {   // K: rows r*16+w*4 .. +4, lane covers (row=+l>>4, chunk=l&15)
                const int row = r * 16 + w * 4 + (l >> 4);
                const int c = (l & 15) ^ (row & 7);
                gload_lds16(Kh + (size_t)(t0 + row) * DH + c * 8,
                            &Kbuf[buf][(r * 16 + w * 4) * 128]);
            }
            {   // V: rows r*32+w*8 .. +8, lane covers (row=+l>>3, chunk=l&7)
                const int d = r * 32 + w * 8 + (l >> 3);
                const int c = (l & 7) ^ (d & 7);
                gload_lds16(Vh + (size_t)d * SEQ + t0 + c * 8,
                            &Vbuf[buf][(r * 32 + w * 8) * 64]);
            }
        }
    };

    int cur = 0;
    stage(0, 0);
    asm volatile("s_waitcnt vmcnt(0)" ::: "memory");
    __syncthreads();

    for (int t0 = 0; t0 < SEQ; t0 += 64) {
        if (t0 + 64 < SEQ) stage(cur ^ 1, t0 + 64);   // prefetch next tile (stays in flight)

        // QK^T for 64 keys, K from LDS
        f32x4 sc[4];
#pragma unroll
        for (int kg = 0; kg < 4; ++kg) sc[kg] = f32x4{0.f, 0.f, 0.f, 0.f};
#pragma unroll
        for (int kg = 0; kg < 4; ++kg) {
            const int trow = kg * 16 + l15;
#pragma unroll
            for (int c = 0; c < 4; ++c) {
                const int cc = (c * 4 + lhi) ^ (trow & 7);
                short8 kf = *(const short8*)(&Kbuf[cur][trow * 128 + cc * 8]);
                sc[kg] = __builtin_amdgcn_mfma_f32_16x16x32_bf16(qf[c], kf, sc[kg], 0, 0, 0);
            }
        }

        // online softmax; score rows r live at row 4*lhi+r, cols kg*16+l15
        float corr[4];
#pragma unroll
        for (int r = 0; r < 4; ++r) {
            float s0 = sc[0][r] * SCALE, s1 = sc[1][r] * SCALE,
                  s2 = sc[2][r] * SCALE, s3 = sc[3][r] * SCALE;
            float mx = fmaxf(fmaxf(s0, s1), fmaxf(s2, s3));
#pragma unroll
            for (int off = 1; off < 16; off <<= 1)
                mx = fmaxf(mx, __shfl_xor(mx, off, 64));
            const float mnew = fmaxf(mrun[r], mx);
            corr[r] = __expf(mrun[r] - mnew);
            const float p0 = __expf(s0 - mnew);
            const float p1 = __expf(s1 - mnew);
            const float p2 = __expf(s2 - mnew);
            const float p3 = __expf(s3 - mnew);
            const int ri = 4 * lhi + r;
            P[w][ri][0 * 16 + l15] = f2bf(p0);
            P[w][ri][1 * 16 + l15] = f2bf(p1);
            P[w][ri][2 * 16 + l15] = f2bf(p2);
            P[w][ri][3 * 16 + l15] = f2bf(p3);
            float ps = p0 + p1 + p2 + p3;
#pragma unroll
            for (int off = 1; off < 16; off <<= 1)
                ps += __shfl_xor(ps, off, 64);
            lrun[r] = lrun[r] * corr[r] + ps;
            mrun[r] = mnew;
        }
        // rescale O
#pragma unroll
        for (int g = 0; g < 8; ++g)
#pragma unroll
            for (int r = 0; r < 4; ++r) o[g][r] *= corr[r];

        __syncthreads();   // P visible (within-wave ds ordering) before PV

        // PV: A = P (rows=q, k=t), B = V tile from LDS
#pragma unroll
        for (int c2 = 0; c2 < 2; ++c2) {
            short8 pa = *(const short8*)(&P[w][l15][c2 * 32 + lhi * 8]);
#pragma unroll
            for (int g = 0; g < 8; ++g) {
                const int dcol = g * 16 + l15;
                const int cc = (c2 * 4 + lhi) ^ (dcol & 7);
                short8 vf = *(const short8*)(&Vbuf[cur][dcol * 64 + cc * 8]);
                o[g] = __builtin_amdgcn_mfma_f32_16x16x32_bf16(pa, vf, o[g], 0, 0, 0);
            }
        }

        asm volatile("s_waitcnt vmcnt(0)" ::: "memory");  // next tile landed
        __syncthreads();                                  // all waves done with cur
        cur ^= 1;
    }

    // epilogue: divide by l, write att[s][h*128+d]
#pragma unroll
    for (int r = 0; r < 4; ++r) {
        const float inv = 1.0f / lrun[r];
        const int row = qb * 64 + w * 16 + 4 * lhi + r;
#pragma unroll
        for (int g = 0; g < 8; ++g) {
            const int col = h * DH + g * 16 + l15;
            att[(size_t)row * (HEADS * DH) + col] = f2bf(o[g][r] * inv);
        }
    }
}

extern "C" void kernel_launch(void* const* d_in, const int* in_sizes, int n_in,
                              void* d_out, int out_size, void* d_ws, size_t ws_size,
                              hipStream_t stream) {
    const float* x  = (const float*)d_in[0];
    const float* Wq = (const float*)d_in[1];
    const float* bq = (const float*)d_in[2];
    const float* Wk = (const float*)d_in[3];
    const float* bk = (const float*)d_in[4];
    const float* Wv = (const float*)d_in[5];
    const float* bv = (const float*)d_in[6];
    const float* Wo = (const float*)d_in[7];
    const float* bo = (const float*)d_in[8];
    float* out = (float*)d_out;

    ushort_t* ws = (ushort_t*)d_ws;
    ushort_t* xp   = ws;                                   // 4096*1024
    ushort_t* Wqt  = xp  + (size_t)SEQ * EMB;              // 16*128*1024
    ushort_t* Wkt  = Wqt + (size_t)HEADS * DH * EMB;
    ushort_t* Wvt  = Wkt + (size_t)HEADS * DH * EMB;
    ushort_t* Wot  = Wvt + (size_t)HEADS * DH * EMB;       // 1024*2048
    ushort_t* Qb   = Wot + (size_t)EMB * (HEADS * DH);     // 16*4096*128
    ushort_t* Kb   = Qb  + (size_t)HEADS * SEQ * DH;
    ushort_t* Vtb  = Kb  + (size_t)HEADS * SEQ * DH;
    ushort_t* attb = Vtb + (size_t)HEADS * SEQ * DH;       // 4096*2048

    prep_x_kernel<<<dim3(SEQ, EMB / 256), 256, 0, stream>>>(x, xp);

    transpose_w_kernel<<<dim3((EMB * DH + 255) / 256, 1, HEADS), 256, 0, stream>>>(Wq, Wqt, EMB, DH);
    transpose_w_kernel<<<dim3((EMB * DH + 255) / 256, 1, HEADS), 256, 0, stream>>>(Wk, Wkt, EMB, DH);
    transpose_w_kernel<<<dim3((EMB * DH + 255) / 256, 1, HEADS), 256, 0, stream>>>(Wv, Wvt, EMB, DH);
    transpose_w_kernel<<<dim3((2048 * 1024 + 255) / 256, 1, 1), 256, 0, stream>>>(Wo, Wot, HEADS * DH, EMB);

    // Q, K: [h][s][d] bf16; V: [h][d][s] bf16
    gemm_bias_kernel<0><<<dim3(SEQ / 64, DH / 64, HEADS), 256, 0, stream>>>(xp, Wqt, bq, Qb, SEQ, DH, EMB);
    gemm_bias_kernel<0><<<dim3(SEQ / 64, DH / 64, HEADS), 256, 0, stream>>>(xp, Wkt, bk, Kb, SEQ, DH, EMB);
    gemm_bias_kernel<1><<<dim3(SEQ / 64, DH / 64, HEADS), 256, 0, stream>>>(xp, Wvt, bv, Vtb, SEQ, DH, EMB);

    attn_kernel<<<dim3(SEQ / 64, HEADS), 256, 0, stream>>>(Qb, Kb, Vtb, attb);

    // out = att @ Wo + bo (fp32 out)
    gemm_bias_kernel<2><<<dim3(SEQ / 64, EMB / 64, 1), 256, 0, stream>>>(attb, Wot, bo, out, SEQ, EMB, HEADS * DH);
}

// Round 6
// 498.806 us; speedup vs baseline: 3.4269x; 2.0514x over previous
//
#include <hip/hip_runtime.h>
#include <hip/hip_bf16.h>

typedef unsigned short ushort_t;
typedef __attribute__((ext_vector_type(8))) short short8;
typedef __attribute__((ext_vector_type(4))) float f32x4;

#define SEQ 4096
#define EMB 1024
#define HEADS 16
#define DH 128
#define SCALE 0.088388347648318447f  /* 1/sqrt(128) */

__device__ __forceinline__ ushort_t f2bf(float f) {
    union { float f; unsigned u; } v; v.f = f;
    unsigned r = v.u + 0x7fffu + ((v.u >> 16) & 1u);
    return (ushort_t)(r >> 16);
}

// async global->LDS, 16B per lane; lds base must be wave-uniform (dest = base + lane*16)
__device__ __forceinline__ void gload_lds16(const ushort_t* g, ushort_t* l) {
    __builtin_amdgcn_global_load_lds(
        (const __attribute__((address_space(1))) void*)g,
        (__attribute__((address_space(3))) void*)l, 16, 0, 0);
}

// xp = x + positional_encoding, cast to bf16
__global__ __launch_bounds__(256) void prep_x_kernel(
    const float* __restrict__ x, ushort_t* __restrict__ xp)
{
    const int s = blockIdx.x;
    const int c = blockIdx.y * 256 + threadIdx.x;
    const int expo = c & ~1;                 // 2*floor(c/2)
    float p = powf(10000.0f, (float)expo);
    float denom = (float)EMB / p;            // inf -> 0 (matches jax fp32)
    float ang = (float)s * denom;
    float pe = (c & 1) ? cosf(ang) : sinf(ang);
    xp[(size_t)s * EMB + c] = f2bf(x[(size_t)s * EMB + c] + pe);
}

// W[b][k][n] f32 -> Wt[b][n][k] bf16, coalesced via 64x64 LDS tile
__global__ __launch_bounds__(256) void transpose_w_kernel(
    const float* __restrict__ W, ushort_t* __restrict__ Wt, int Kd, int Nd)
{
    const int b = blockIdx.z;
    const int k0 = blockIdx.x * 64, n0 = blockIdx.y * 64;
    const int tx = threadIdx.x & 63, ty = threadIdx.x >> 6;
    __shared__ ushort_t t[64][65];
    const float* Wb = W + (size_t)b * Kd * Nd;
    ushort_t* Wtb = Wt + (size_t)b * Nd * Kd;
#pragma unroll
    for (int i = 0; i < 16; ++i) {
        const int r = ty + i * 4;
        t[r][tx] = f2bf(Wb[(size_t)(k0 + r) * Nd + n0 + tx]);   // coalesced read
    }
    __syncthreads();
#pragma unroll
    for (int i = 0; i < 16; ++i) {
        const int r = ty + i * 4;
        Wtb[(size_t)(n0 + r) * Kd + k0 + tx] = t[tx][r];        // coalesced write
    }
}

// C = A(bf16, MxK) @ Bt(bf16, NxK)^T + bias, 128x128 tile, 4 waves (2x2), BK=32,
// double-buffered LDS via global_load_lds w16 (m97 structure; 64B row stride -> conflict-free).
// MODE 0: A shared, Bt per-head; bias[h*N+col]; bf16 out [(h*M+row)*N+col]   (Q,K)
// MODE 3: A per-head, Bt shared;  bias[h*M+row]; bf16 out [(h*M+row)*N+col]  (V^T)
// MODE 2: batch=1; f32 out [row*N+col]                                       (final)
template <int MODE>
__global__ __launch_bounds__(256) void gemm_bias_kernel(
    const ushort_t* __restrict__ A, const ushort_t* __restrict__ Bt,
    const float* __restrict__ bias, void* __restrict__ Cout,
    int M, int N, int K)
{
    const int mb = blockIdx.x, nb = blockIdx.y, h = blockIdx.z;
    const int tid = threadIdx.x;
    const int w = tid >> 6;
    const int l = tid & 63;
    const int l15 = l & 15, lhi = l >> 4;
    const int wm = w >> 1, wn = w & 1;        // 2x2 wave grid, 64x64 each

    __shared__ ushort_t Abuf[2][128 * 32];
    __shared__ ushort_t Bbuf[2][128 * 32];

    const ushort_t* Ah = (MODE == 3) ? A + (size_t)h * M * K : A;
    const ushort_t* Bh = (MODE == 0) ? Bt + (size_t)h * N * K : Bt;

    const int m0 = mb * 128, n0 = nb * 128;

    f32x4 acc[4][4];
#pragma unroll
    for (int f = 0; f < 4; ++f)
#pragma unroll
        for (int g = 0; g < 4; ++g) acc[f][g] = f32x4{0.f, 0.f, 0.f, 0.f};

    // stage one 128x32 tile pair; per wave: 2 issues x (A,B), lane covers 16 rows x 32k
    const int srow = w * 16 + (l >> 2);       // row within 64-row half
    const int sk = (l & 3) * 8;
    auto stage = [&](int buf, int kt) {
        const int k0 = kt * 32;
#pragma unroll
        for (int i = 0; i < 2; ++i) {
            gload_lds16(Ah + (size_t)(m0 + i * 64 + srow) * K + k0 + sk,
                        &Abuf[buf][(i * 64 + w * 16) * 32]);
            gload_lds16(Bh + (size_t)(n0 + i * 64 + srow) * K + k0 + sk,
                        &Bbuf[buf][(i * 64 + w * 16) * 32]);
        }
    };

    const int nk = K / 32;
    int cur = 0;
    stage(0, 0);
    asm volatile("s_waitcnt vmcnt(0)" ::: "memory");
    __syncthreads();

    for (int kt = 0; kt < nk; ++kt) {
        if (kt + 1 < nk) stage(cur ^ 1, kt + 1);

        short8 af[4], bf[4];
#pragma unroll
        for (int f = 0; f < 4; ++f)
            af[f] = *(const short8*)(&Abuf[cur][(wm * 64 + f * 16 + l15) * 32 + lhi * 8]);
#pragma unroll
        for (int g = 0; g < 4; ++g)
            bf[g] = *(const short8*)(&Bbuf[cur][(wn * 64 + g * 16 + l15) * 32 + lhi * 8]);
#pragma unroll
        for (int f = 0; f < 4; ++f)
#pragma unroll
            for (int g = 0; g < 4; ++g)
                acc[f][g] = __builtin_amdgcn_mfma_f32_16x16x32_bf16(af[f], bf[g], acc[f][g], 0, 0, 0);

        asm volatile("s_waitcnt vmcnt(0)" ::: "memory");
        __syncthreads();
        cur ^= 1;
    }

#pragma unroll
    for (int f = 0; f < 4; ++f) {
        const int row0 = m0 + wm * 64 + f * 16 + 4 * lhi;
#pragma unroll
        for (int g = 0; g < 4; ++g) {
            const int col = n0 + wn * 64 + g * 16 + l15;
            float bv;
            if (MODE == 0) bv = bias[(size_t)h * N + col];
            else if (MODE == 3) bv = 0.f;  // per-row bias added below
            else bv = bias[col];
#pragma unroll
            for (int r = 0; r < 4; ++r) {
                const int row = row0 + r;
                float val = acc[f][g][r];
                if (MODE == 3) val += bias[(size_t)h * M + row];
                else val += bv;
                if (MODE == 2)
                    ((float*)Cout)[(size_t)row * N + col] = val;
                else
                    ((ushort_t*)Cout)[((size_t)h * M + row) * N + col] = f2bf(val);
            }
        }
    }
}

// Flash attention: Q[h][s][d], K[h][t][d], Vt[h][d][t] (bf16) -> att[s][h*128+d] (bf16)
__global__ __launch_bounds__(256) void attn_kernel(
    const ushort_t* __restrict__ Q, const ushort_t* __restrict__ K,
    const ushort_t* __restrict__ Vt, ushort_t* __restrict__ att)
{
    const int qb = blockIdx.x;       // 64-row q block
    const int h = blockIdx.y;
    const int tid = threadIdx.x;
    const int w = tid >> 6;
    const int l = tid & 63;
    const int l15 = l & 15, lhi = l >> 4;

    __shared__ ushort_t Kbuf[2][64 * 128];   // [t][d], swizzled
    __shared__ ushort_t Vbuf[2][128 * 64];   // [d][t], swizzled
    __shared__ ushort_t P[4][16][64];        // per-wave P tile

    const ushort_t* Qh = Q + (size_t)h * SEQ * DH;
    const ushort_t* Kh = K + (size_t)h * SEQ * DH;
    const ushort_t* Vh = Vt + (size_t)h * DH * SEQ;

    short8 qf[4];
    const int qrow = qb * 64 + w * 16 + l15;
#pragma unroll
    for (int c = 0; c < 4; ++c)
        qf[c] = *(const short8*)(Qh + (size_t)qrow * DH + c * 32 + lhi * 8);

    f32x4 o[8];
#pragma unroll
    for (int g = 0; g < 8; ++g) o[g] = f32x4{0.f, 0.f, 0.f, 0.f};
    float mrun[4], lrun[4];
#pragma unroll
    for (int r = 0; r < 4; ++r) { mrun[r] = -1e30f; lrun[r] = 0.f; }

    auto stage = [&](int buf, int t0) {
#pragma unroll
        for (int r = 0; r < 4; ++r) {
            {
                const int row = r * 16 + w * 4 + (l >> 4);
                const int c = (l & 15) ^ (row & 7);
                gload_lds16(Kh + (size_t)(t0 + row) * DH + c * 8,
                            &Kbuf[buf][(r * 16 + w * 4) * 128]);
            }
            {
                const int d = r * 32 + w * 8 + (l >> 3);
                const int c = (l & 7) ^ (d & 7);
                gload_lds16(Vh + (size_t)d * SEQ + t0 + c * 8,
                            &Vbuf[buf][(r * 32 + w * 8) * 64]);
            }
        }
    };

    int cur = 0;
    stage(0, 0);
    asm volatile("s_waitcnt vmcnt(0)" ::: "memory");
    __syncthreads();

    for (int t0 = 0; t0 < SEQ; t0 += 64) {
        if (t0 + 64 < SEQ) stage(cur ^ 1, t0 + 64);

        f32x4 sc[4];
#pragma unroll
        for (int kg = 0; kg < 4; ++kg) sc[kg] = f32x4{0.f, 0.f, 0.f, 0.f};
#pragma unroll
        for (int kg = 0; kg < 4; ++kg) {
            const int trow = kg * 16 + l15;
#pragma unroll
            for (int c = 0; c < 4; ++c) {
                const int cc = (c * 4 + lhi) ^ (trow & 7);
                short8 kf = *(const short8*)(&Kbuf[cur][trow * 128 + cc * 8]);
                sc[kg] = __builtin_amdgcn_mfma_f32_16x16x32_bf16(qf[c], kf, sc[kg], 0, 0, 0);
            }
        }

        float corr[4];
#pragma unroll
        for (int r = 0; r < 4; ++r) {
            float s0 = sc[0][r] * SCALE, s1 = sc[1][r] * SCALE,
                  s2 = sc[2][r] * SCALE, s3 = sc[3][r] * SCALE;
            float mx = fmaxf(fmaxf(s0, s1), fmaxf(s2, s3));
#pragma unroll
            for (int off = 1; off < 16; off <<= 1)
                mx = fmaxf(mx, __shfl_xor(mx, off, 64));
            const float mnew = fmaxf(mrun[r], mx);
            corr[r] = __expf(mrun[r] - mnew);
            const float p0 = __expf(s0 - mnew);
            const float p1 = __expf(s1 - mnew);
            const float p2 = __expf(s2 - mnew);
            const float p3 = __expf(s3 - mnew);
            const int ri = 4 * lhi + r;
            P[w][ri][0 * 16 + l15] = f2bf(p0);
            P[w][ri][1 * 16 + l15] = f2bf(p1);
            P[w][ri][2 * 16 + l15] = f2bf(p2);
            P[w][ri][3 * 16 + l15] = f2bf(p3);
            float ps = p0 + p1 + p2 + p3;
#pragma unroll
            for (int off = 1; off < 16; off <<= 1)
                ps += __shfl_xor(ps, off, 64);
            lrun[r] = lrun[r] * corr[r] + ps;
            mrun[r] = mnew;
        }
#pragma unroll
        for (int g = 0; g < 8; ++g)
#pragma unroll
            for (int r = 0; r < 4; ++r) o[g][r] *= corr[r];

        __syncthreads();

#pragma unroll
        for (int c2 = 0; c2 < 2; ++c2) {
            short8 pa = *(const short8*)(&P[w][l15][c2 * 32 + lhi * 8]);
#pragma unroll
            for (int g = 0; g < 8; ++g) {
                const int dcol = g * 16 + l15;
                const int cc = (c2 * 4 + lhi) ^ (dcol & 7);
                short8 vf = *(const short8*)(&Vbuf[cur][dcol * 64 + cc * 8]);
                o[g] = __builtin_amdgcn_mfma_f32_16x16x32_bf16(pa, vf, o[g], 0, 0, 0);
            }
        }

        asm volatile("s_waitcnt vmcnt(0)" ::: "memory");
        __syncthreads();
        cur ^= 1;
    }

#pragma unroll
    for (int r = 0; r < 4; ++r) {
        const float inv = 1.0f / lrun[r];
        const int row = qb * 64 + w * 16 + 4 * lhi + r;
#pragma unroll
        for (int g = 0; g < 8; ++g) {
            const int col = h * DH + g * 16 + l15;
            att[(size_t)row * (HEADS * DH) + col] = f2bf(o[g][r] * inv);
        }
    }
}

extern "C" void kernel_launch(void* const* d_in, const int* in_sizes, int n_in,
                              void* d_out, int out_size, void* d_ws, size_t ws_size,
                              hipStream_t stream) {
    const float* x  = (const float*)d_in[0];
    const float* Wq = (const float*)d_in[1];
    const float* bq = (const float*)d_in[2];
    const float* Wk = (const float*)d_in[3];
    const float* bk = (const float*)d_in[4];
    const float* Wv = (const float*)d_in[5];
    const float* bv = (const float*)d_in[6];
    const float* Wo = (const float*)d_in[7];
    const float* bo = (const float*)d_in[8];
    float* out = (float*)d_out;

    ushort_t* ws = (ushort_t*)d_ws;
    ushort_t* xp   = ws;                                   // 4096*1024
    ushort_t* Wqt  = xp  + (size_t)SEQ * EMB;              // 16*128*1024
    ushort_t* Wkt  = Wqt + (size_t)HEADS * DH * EMB;
    ushort_t* Wvt  = Wkt + (size_t)HEADS * DH * EMB;
    ushort_t* Wot  = Wvt + (size_t)HEADS * DH * EMB;       // 1024*2048
    ushort_t* Qb   = Wot + (size_t)EMB * (HEADS * DH);     // 16*4096*128
    ushort_t* Kb   = Qb  + (size_t)HEADS * SEQ * DH;
    ushort_t* Vtb  = Kb  + (size_t)HEADS * SEQ * DH;
    ushort_t* attb = Vtb + (size_t)HEADS * SEQ * DH;       // 4096*2048

    prep_x_kernel<<<dim3(SEQ, EMB / 256), 256, 0, stream>>>(x, xp);

    // W transposes (coalesced LDS tiles)
    transpose_w_kernel<<<dim3(EMB / 64, DH / 64, HEADS), 256, 0, stream>>>(Wq, Wqt, EMB, DH);
    transpose_w_kernel<<<dim3(EMB / 64, DH / 64, HEADS), 256, 0, stream>>>(Wk, Wkt, EMB, DH);
    transpose_w_kernel<<<dim3(EMB / 64, DH / 64, HEADS), 256, 0, stream>>>(Wv, Wvt, EMB, DH);
    transpose_w_kernel<<<dim3((HEADS * DH) / 64, EMB / 64, 1), 256, 0, stream>>>(Wo, Wot, HEADS * DH, EMB);

    // Q, K: [h][s][d]; V computed transposed: [h][d][s]
    gemm_bias_kernel<0><<<dim3(SEQ / 128, DH / 128, HEADS), 256, 0, stream>>>(xp, Wqt, bq, Qb, SEQ, DH, EMB);
    gemm_bias_kernel<0><<<dim3(SEQ / 128, DH / 128, HEADS), 256, 0, stream>>>(xp, Wkt, bk, Kb, SEQ, DH, EMB);
    gemm_bias_kernel<3><<<dim3(DH / 128, SEQ / 128, HEADS), 256, 0, stream>>>(Wvt, xp, bv, Vtb, DH, SEQ, EMB);

    attn_kernel<<<dim3(SEQ / 64, HEADS), 256, 0, stream>>>(Qb, Kb, Vtb, attb);

    // out = att @ Wo + bo (fp32 out)
    gemm_bias_kernel<2><<<dim3(SEQ / 128, EMB / 128, 1), 256, 0, stream>>>(attb, Wot, bo, out, SEQ, EMB, HEADS * DH);
}

// Round 8
// 415.475 us; speedup vs baseline: 4.1142x; 1.2006x over previous
//
#include <hip/hip_runtime.h>
#include <hip/hip_bf16.h>

typedef unsigned short ushort_t;
typedef __attribute__((ext_vector_type(8))) short short8;
typedef __attribute__((ext_vector_type(4))) float f32x4;
typedef __attribute__((ext_vector_type(16))) float f32x16;
typedef __attribute__((ext_vector_type(2))) int v2i;
typedef __attribute__((ext_vector_type(4))) int i32x4;

#define SEQ 4096
#define EMB 1024
#define HEADS 16
#define DH 128
#define SCALE 0.088388347648318447f  /* 1/sqrt(128) */

__device__ __forceinline__ ushort_t f2bf(float f) {
    union { float f; unsigned u; } v; v.f = f;
    unsigned r = v.u + 0x7fffu + ((v.u >> 16) & 1u);
    return (ushort_t)(r >> 16);
}

__device__ __forceinline__ int cvt_pk_bf16(float lo, float hi) {
    int r;
    asm("v_cvt_pk_bf16_f32 %0, %1, %2" : "=v"(r) : "v"(lo), "v"(hi));
    return r;
}

// cross 32-lane-half combine: every lane gets op(x[l], x[l^32])
__device__ __forceinline__ float cross32_max(float x) {
    v2i r = __builtin_amdgcn_permlane32_swap(__float_as_int(x), __float_as_int(x), false, false);
    return fmaxf(__int_as_float(r.x), __int_as_float(r.y));
}
__device__ __forceinline__ float cross32_add(float x) {
    v2i r = __builtin_amdgcn_permlane32_swap(__float_as_int(x), __float_as_int(x), false, false);
    return __int_as_float(r.x) + __int_as_float(r.y);
}

// async global->LDS, 16B per lane; lds base must be wave-uniform (dest = base + lane*16)
__device__ __forceinline__ void gload_lds16(const ushort_t* g, ushort_t* l) {
    __builtin_amdgcn_global_load_lds(
        (const __attribute__((address_space(1))) void*)g,
        (__attribute__((address_space(3))) void*)l, 16, 0, 0);
}

// xp = x + positional_encoding, cast to bf16
__global__ __launch_bounds__(256) void prep_x_kernel(
    const float* __restrict__ x, ushort_t* __restrict__ xp)
{
    const int s = blockIdx.x;
    const int c = blockIdx.y * 256 + threadIdx.x;
    const int expo = c & ~1;
    float p = powf(10000.0f, (float)expo);
    float denom = (float)EMB / p;            // inf -> 0 (matches jax fp32)
    float ang = (float)s * denom;
    float pe = (c & 1) ? cosf(ang) : sinf(ang);
    xp[(size_t)s * EMB + c] = f2bf(x[(size_t)s * EMB + c] + pe);
}

// W[b][k][n] f32 -> Wt[b][n][k] bf16, coalesced via 64x64 LDS tile
__global__ __launch_bounds__(256) void transpose_w_kernel(
    const float* __restrict__ W, ushort_t* __restrict__ Wt, int Kd, int Nd)
{
    const int b = blockIdx.z;
    const int k0 = blockIdx.x * 64, n0 = blockIdx.y * 64;
    const int tx = threadIdx.x & 63, ty = threadIdx.x >> 6;
    __shared__ ushort_t t[64][65];
    const float* Wb = W + (size_t)b * Kd * Nd;
    ushort_t* Wtb = Wt + (size_t)b * Nd * Kd;
#pragma unroll
    for (int i = 0; i < 16; ++i) {
        const int r = ty + i * 4;
        t[r][tx] = f2bf(Wb[(size_t)(k0 + r) * Nd + n0 + tx]);
    }
    __syncthreads();
#pragma unroll
    for (int i = 0; i < 16; ++i) {
        const int r = ty + i * 4;
        Wtb[(size_t)(n0 + r) * Kd + k0 + tx] = t[tx][r];
    }
}

// C = A(bf16, MxK) @ Bt(bf16, NxK)^T + bias, 128x128 tile, 4 waves (2x2), BK=32.
// MODE 0: A shared, Bt per-head; bias[h*N+col]; bf16 out [(h*M+row)*N+col]   (K)
// MODE 4: like MODE 0 but out scaled by SCALE                                 (Q)
// MODE 3: A per-head, Bt shared;  bias[h*M+row]; bf16 out [(h*M+row)*N+col]  (V^T)
// MODE 2: batch=1; f32 out [row*N+col]                                       (final)
template <int MODE>
__global__ __launch_bounds__(256) void gemm_bias_kernel(
    const ushort_t* __restrict__ A, const ushort_t* __restrict__ Bt,
    const float* __restrict__ bias, void* __restrict__ Cout,
    int M, int N, int K)
{
    const int mb = blockIdx.x, nb = blockIdx.y, h = blockIdx.z;
    const int tid = threadIdx.x;
    const int w = tid >> 6;
    const int l = tid & 63;
    const int l15 = l & 15, lhi = l >> 4;
    const int wm = w >> 1, wn = w & 1;

    __shared__ ushort_t Abuf[2][128 * 32];
    __shared__ ushort_t Bbuf[2][128 * 32];

    const ushort_t* Ah = (MODE == 3) ? A + (size_t)h * M * K : A;
    const ushort_t* Bh = (MODE == 0 || MODE == 4) ? Bt + (size_t)h * N * K : Bt;

    const int m0 = mb * 128, n0 = nb * 128;

    f32x4 acc[4][4];
#pragma unroll
    for (int f = 0; f < 4; ++f)
#pragma unroll
        for (int g = 0; g < 4; ++g) acc[f][g] = f32x4{0.f, 0.f, 0.f, 0.f};

    const int srow = w * 16 + (l >> 2);
    const int sk = (l & 3) * 8;
    auto stage = [&](int buf, int kt) {
        const int k0 = kt * 32;
#pragma unroll
        for (int i = 0; i < 2; ++i) {
            gload_lds16(Ah + (size_t)(m0 + i * 64 + srow) * K + k0 + sk,
                        &Abuf[buf][(i * 64 + w * 16) * 32]);
            gload_lds16(Bh + (size_t)(n0 + i * 64 + srow) * K + k0 + sk,
                        &Bbuf[buf][(i * 64 + w * 16) * 32]);
        }
    };

    const int nk = K / 32;
    int cur = 0;
    stage(0, 0);
    asm volatile("s_waitcnt vmcnt(0)" ::: "memory");
    __syncthreads();

    for (int kt = 0; kt < nk; ++kt) {
        if (kt + 1 < nk) stage(cur ^ 1, kt + 1);

        short8 af[4], bf[4];
#pragma unroll
        for (int f = 0; f < 4; ++f)
            af[f] = *(const short8*)(&Abuf[cur][(wm * 64 + f * 16 + l15) * 32 + lhi * 8]);
#pragma unroll
        for (int g = 0; g < 4; ++g)
            bf[g] = *(const short8*)(&Bbuf[cur][(wn * 64 + g * 16 + l15) * 32 + lhi * 8]);
#pragma unroll
        for (int f = 0; f < 4; ++f)
#pragma unroll
            for (int g = 0; g < 4; ++g)
                acc[f][g] = __builtin_amdgcn_mfma_f32_16x16x32_bf16(af[f], bf[g], acc[f][g], 0, 0, 0);

        asm volatile("s_waitcnt vmcnt(0)" ::: "memory");
        __syncthreads();
        cur ^= 1;
    }

#pragma unroll
    for (int f = 0; f < 4; ++f) {
        const int row0 = m0 + wm * 64 + f * 16 + 4 * lhi;
#pragma unroll
        for (int g = 0; g < 4; ++g) {
            const int col = n0 + wn * 64 + g * 16 + l15;
            float bv;
            if (MODE == 0 || MODE == 4) bv = bias[(size_t)h * N + col];
            else if (MODE == 3) bv = 0.f;
            else bv = bias[col];
#pragma unroll
            for (int r = 0; r < 4; ++r) {
                const int row = row0 + r;
                float val = acc[f][g][r];
                if (MODE == 3) val += bias[(size_t)h * M + row];
                else val += bv;
                if (MODE == 4) val *= SCALE;
                if (MODE == 2)
                    ((float*)Cout)[(size_t)row * N + col] = val;
                else
                    ((ushort_t*)Cout)[((size_t)h * M + row) * N + col] = f2bf(val);
            }
        }
    }
}

// Flash attention, 32x32 swapped-operand structure.
// Q[h][s][d] (pre-scaled), K[h][t][d], Vt[h][d][t] -> att[s][h*128+d] (bf16)
// Block: 4 waves x 32 q-rows = 128 q. KVBLK=64, K/V double-buffered in LDS.
// QK^T: mfma(K,Q) -> P[t][q], q = lane&31 -> softmax fully in-register.
// PV: mfma(Vt,P) -> O^T[d][q], corr/lrun lane-local.
// LDS swizzle (both sides, involution): chunk' = chunk ^ mask(row),
//   mask_k(row) = (row^(row>>3))&15, mask_v(row) = (row^(row>>3))&7.
__global__ __launch_bounds__(256) void attn_kernel(
    const ushort_t* __restrict__ Q, const ushort_t* __restrict__ K,
    const ushort_t* __restrict__ Vt, ushort_t* __restrict__ att)
{
    const int qb = blockIdx.x;       // 128-row q block
    const int h = blockIdx.y;
    const int tid = threadIdx.x;
    const int w = tid >> 6;
    const int l = tid & 63;
    const int l31 = l & 31;
    const int hi = l >> 5;

    __shared__ ushort_t Kbuf[2][64 * 128];   // [t][d]
    __shared__ ushort_t Vbuf[2][128 * 64];   // [d][t]

    const ushort_t* Qh = Q + (size_t)h * SEQ * DH;
    const ushort_t* Kh = K + (size_t)h * SEQ * DH;
    const ushort_t* Vh = Vt + (size_t)h * DH * SEQ;

    // Q fragments (B-operand): lane holds Q[q0+l31][c*16 + hi*8 .. +8]
    const int qrow = qb * 128 + w * 32 + l31;
    short8 qf[8];
#pragma unroll
    for (int c = 0; c < 8; ++c)
        qf[c] = *(const short8*)(Qh + (size_t)qrow * DH + c * 16 + hi * 8);

    f32x16 o[4];
#pragma unroll
    for (int dblk = 0; dblk < 4; ++dblk)
#pragma unroll
        for (int i = 0; i < 16; ++i) o[dblk][i] = 0.f;
    float mrun = -1e30f, lrun = 0.f;

    // stage 64-key tile: K 64x128 (16 chunks/row), V 128x64 (8 chunks/row)
    auto stage = [&](int buf, int t0) {
#pragma unroll
        for (int i = 0; i < 4; ++i) {
            const int L = i * 256 + tid;
            {   // K: row = L>>4, chunk' = L&15, src chunk = chunk' ^ mask_k(row)
                const int row = L >> 4;
                const int c = (L & 15) ^ ((row ^ (row >> 3)) & 15);
                gload_lds16(Kh + (size_t)(t0 + row) * DH + c * 8,
                            &Kbuf[buf][(L & ~63) * 8]);
            }
            {   // V: row = L>>3, chunk' = L&7, src chunk = chunk' ^ mask_v(row)
                const int row = L >> 3;
                const int c = (L & 7) ^ ((row ^ (row >> 3)) & 7);
                gload_lds16(Vh + (size_t)row * SEQ + t0 + c * 8,
                            &Vbuf[buf][(L & ~63) * 8]);
            }
        }
    };

    int cur = 0;
    stage(0, 0);
    asm volatile("s_waitcnt vmcnt(0)" ::: "memory");
    __syncthreads();

    for (int t0 = 0; t0 < SEQ; t0 += 64) {
        if (t0 + 64 < SEQ) stage(cur ^ 1, t0 + 64);

        // QK^T: P[t][q]; lane: q=l31, t = crow(reg,hi)+32*tb, crow=(r&3)+8*(r>>2)+4*hi
        f32x16 p0, p1;
#pragma unroll
        for (int i = 0; i < 16; ++i) { p0[i] = 0.f; p1[i] = 0.f; }
#pragma unroll
        for (int c = 0; c < 8; ++c) {
            const int r0 = l31;
            const int ch0 = ((c * 2 + hi) ^ ((r0 ^ (r0 >> 3)) & 15)) * 8;     // rows 0..31
            short8 k0 = *(const short8*)(&Kbuf[cur][r0 * 128 + ch0]);
            p0 = __builtin_amdgcn_mfma_f32_32x32x16_bf16(k0, qf[c], p0, 0, 0, 0);
            const int r1 = 32 + l31;
            const int ch1 = ((c * 2 + hi) ^ ((r1 ^ (r1 >> 3)) & 15)) * 8;     // rows 32..63
            short8 k1 = *(const short8*)(&Kbuf[cur][r1 * 128 + ch1]);
            p1 = __builtin_amdgcn_mfma_f32_32x32x16_bf16(k1, qf[c], p1, 0, 0, 0);
        }

        // in-register online softmax for q-row l31 (partner lane l^32 holds other half)
        float mx = fmaxf(p0[0], p1[0]);
#pragma unroll
        for (int i = 1; i < 16; ++i) mx = fmaxf(mx, fmaxf(p0[i], p1[i]));
        mx = cross32_max(mx);

        const float mnew = fmaxf(mrun, mx);
        if (!__all(mx - mrun <= 8.0f)) {     // defer-max (THR=8): skip rescale when safe
            const float corr = __expf(mrun - mnew);
            lrun *= corr;
#pragma unroll
            for (int dblk = 0; dblk < 4; ++dblk)
#pragma unroll
                for (int i = 0; i < 16; ++i) o[dblk][i] *= corr;
            mrun = mnew;
        }
#pragma unroll
        for (int i = 0; i < 16; ++i) { p0[i] = __expf(p0[i] - mrun); p1[i] = __expf(p1[i] - mrun); }
        float ps = 0.f;
#pragma unroll
        for (int i = 0; i < 16; ++i) ps += p0[i] + p1[i];
        lrun += cross32_add(ps);

        // P -> bf16 PV A-fragments (T12): per 16-t block, 4 cvt_pk + 2 permlane32_swap.
        // swap(A_,C_) = (w0, w2): w0 = {A_.low | C_.low}, w2 = {A_.high | C_.high}.
        short8 pa[4];
#pragma unroll
        for (int b = 0; b < 4; ++b) {
            const f32x16& psrc = (b < 2) ? p0 : p1;
            const int r0 = (b & 1) * 8;
            const int A_ = cvt_pk_bf16(psrc[r0 + 0], psrc[r0 + 1]);
            const int B_ = cvt_pk_bf16(psrc[r0 + 2], psrc[r0 + 3]);
            const int C_ = cvt_pk_bf16(psrc[r0 + 4], psrc[r0 + 5]);
            const int D_ = cvt_pk_bf16(psrc[r0 + 6], psrc[r0 + 7]);
            v2i s1 = __builtin_amdgcn_permlane32_swap(A_, C_, false, false); // .x=w0 .y=w2
            v2i s2 = __builtin_amdgcn_permlane32_swap(B_, D_, false, false); // .x=w1 .y=w3
            i32x4 wv; wv.x = s1.x; wv.y = s2.x; wv.z = s1.y; wv.w = s2.y;
            pa[b] = __builtin_bit_cast(short8, wv);
        }

        // PV: O^T[d][q] += Vt[d][t] P[t][q]
#pragma unroll
        for (int dblk = 0; dblk < 4; ++dblk) {
            const int vrow = dblk * 32 + l31;
#pragma unroll
            for (int ks = 0; ks < 4; ++ks) {
                const int ch = ((ks * 2 + hi) ^ ((vrow ^ (vrow >> 3)) & 7)) * 8;
                short8 vt = *(const short8*)(&Vbuf[cur][vrow * 64 + ch]);
                o[dblk] = __builtin_amdgcn_mfma_f32_32x32x16_bf16(vt, pa[ks], o[dblk], 0, 0, 0);
            }
        }

        asm volatile("s_waitcnt vmcnt(0)" ::: "memory");
        __syncthreads();
        cur ^= 1;
    }

    // epilogue: att[q][h*128+d] = O^T[d][q]/lrun ; d = dblk*32 + (2j&3)+8*(j>>1)+4*hi
    const float inv = 1.0f / lrun;
    ushort_t* arow = att + (size_t)qrow * (HEADS * DH) + h * DH;
#pragma unroll
    for (int dblk = 0; dblk < 4; ++dblk)
#pragma unroll
        for (int j = 0; j < 8; ++j) {
            const int d = dblk * 32 + ((2 * j) & 3) + 8 * (j >> 1) + 4 * hi;
            const int pk = cvt_pk_bf16(o[dblk][2 * j] * inv, o[dblk][2 * j + 1] * inv);
            *(int*)(arow + d) = pk;
        }
}

extern "C" void kernel_launch(void* const* d_in, const int* in_sizes, int n_in,
                              void* d_out, int out_size, void* d_ws, size_t ws_size,
                              hipStream_t stream) {
    const float* x  = (const float*)d_in[0];
    const float* Wq = (const float*)d_in[1];
    const float* bq = (const float*)d_in[2];
    const float* Wk = (const float*)d_in[3];
    const float* bk = (const float*)d_in[4];
    const float* Wv = (const float*)d_in[5];
    const float* bv = (const float*)d_in[6];
    const float* Wo = (const float*)d_in[7];
    const float* bo = (const float*)d_in[8];
    float* out = (float*)d_out;

    ushort_t* ws = (ushort_t*)d_ws;
    ushort_t* xp   = ws;
    ushort_t* Wqt  = xp  + (size_t)SEQ * EMB;
    ushort_t* Wkt  = Wqt + (size_t)HEADS * DH * EMB;
    ushort_t* Wvt  = Wkt + (size_t)HEADS * DH * EMB;
    ushort_t* Wot  = Wvt + (size_t)HEADS * DH * EMB;
    ushort_t* Qb   = Wot + (size_t)EMB * (HEADS * DH);
    ushort_t* Kb   = Qb  + (size_t)HEADS * SEQ * DH;
    ushort_t* Vtb  = Kb  + (size_t)HEADS * SEQ * DH;
    ushort_t* attb = Vtb + (size_t)HEADS * SEQ * DH;

    prep_x_kernel<<<dim3(SEQ, EMB / 256), 256, 0, stream>>>(x, xp);

    transpose_w_kernel<<<dim3(EMB / 64, DH / 64, HEADS), 256, 0, stream>>>(Wq, Wqt, EMB, DH);
    transpose_w_kernel<<<dim3(EMB / 64, DH / 64, HEADS), 256, 0, stream>>>(Wk, Wkt, EMB, DH);
    transpose_w_kernel<<<dim3(EMB / 64, DH / 64, HEADS), 256, 0, stream>>>(Wv, Wvt, EMB, DH);
    transpose_w_kernel<<<dim3((HEADS * DH) / 64, EMB / 64, 1), 256, 0, stream>>>(Wo, Wot, HEADS * DH, EMB);

    // Q pre-scaled by 1/sqrt(dk); K normal; V computed transposed [h][d][s]
    gemm_bias_kernel<4><<<dim3(SEQ / 128, DH / 128, HEADS), 256, 0, stream>>>(xp, Wqt, bq, Qb, SEQ, DH, EMB);
    gemm_bias_kernel<0><<<dim3(SEQ / 128, DH / 128, HEADS), 256, 0, stream>>>(xp, Wkt, bk, Kb, SEQ, DH, EMB);
    gemm_bias_kernel<3><<<dim3(DH / 128, SEQ / 128, HEADS), 256, 0, stream>>>(Wvt, xp, bv, Vtb, DH, SEQ, EMB);

    attn_kernel<<<dim3(SEQ / 128, HEADS), 256, 0, stream>>>(Qb, Kb, Vtb, attb);

    gemm_bias_kernel<2><<<dim3(SEQ / 128, EMB / 128, 1), 256, 0, stream>>>(attb, Wot, bo, out, SEQ, EMB, HEADS * DH);
}